// Round 5
// baseline (85.005 us; speedup 1.0000x reference)
//
#include <hip/hip_runtime.h>
#include <math.h>

// Problem dims (fixed by reference)
#define BDIM 2048
#define ODIM 256
#define IDIM 256
#define NZ   16                     // j-splits
#define JBLK (IDIM / NZ)            // 16 j per block
#define NJQ  (JBLK / 4)             // 4 j-quads
#define ZBASE ((float)(IDIM / NZ))  // 16.0f; per-z share of the +IDIM base

typedef float v2f __attribute__((ext_vector_type(2)));

// out[b,o] = IDIM + C * sum_j 1/(D - 2at*cos(phi0 + x[b,j] + p[o,j]))
//   C = (t^2-1)(1-a^2),  D = 1+(at)^2
// cos(x'+p) = cos x' cos p - sin x' sin p =>
//   den = D + mc*pc + ms*ps,  mc=-2at*cos(phi0+x), ms=2at*sin(phi0+x)
//
// R14: two-component model fit from R9/R10/R13:
//   t ~= 320us/(waves_per_CU) + LDS_wave_insts * 12cyc
// (R9: 20+10=30 vs 32; R10: 40+5=45 vs 47; R13: 13+15=29 vs 30.5).
// => raise waves/CU WITHOUT raising LDS traffic. At NZ=8 occupancy is
// LDS-size-bound (33.8KB -> 4 blocks/CU). NZ=16 halves LDS to 17.4KB
// while keeping the 256-thr 4b x 4o microtile (4 B/cell-j, total LDS
// insts unchanged at 524k). VGPR becomes the binder: launch_bounds(256,6)
// caps at 85 (~90 working set, minor squeeze) -> 6 blocks/CU = 24
// waves/CU with R9's LDS traffic. Atomics double to 8.4M: R12 proved
// atomics ~free. Pred: 13.3 + 10.2 ~= 24us kernel.

__global__ __launch_bounds__(256, 6)
void photonic_fused(const float* __restrict__ X,   // [BDIM][IDIM]
                    const float* __restrict__ P,   // [ODIM][IDIM]
                    float* __restrict__ Out,       // [BDIM][ODIM] (+= semantics)
                    float phi0, float m2at, float p2at,
                    float Dc, float Cnum) {
    __shared__ float4 As4[64][2 * NJQ + 1];  // [64][9] = 9216 B (col 8 = pad; +4 banks/row)
    __shared__ float4 SP4[JBLK][2][16];      // [16][2][16] = 8192 B

    const int tid = threadIdx.x;
    const int tx  = tid & 15;            // o sub-index
    const int ty  = tid >> 4;            // b sub-index 0..15
    const int o0  = blockIdx.x * 64;
    const int b0  = blockIdx.y * 64;
    const int j0  = blockIdx.z * JBLK;

    // ---- fused prologue: one float4 of X and P per thread ----
    {
        const int r  = tid >> 2;         // 0..63 : row (b for X, o for P)
        const int jq = tid & 3;          // 0..3  : j-quad
        float s0, c0, s1, c1, s2, c2, s3, c3;

        float4 x = *(const float4*)(X + (size_t)(b0 + r) * IDIM + j0 + 4 * jq);
        __sincosf(phi0 + x.x, &s0, &c0);
        __sincosf(phi0 + x.y, &s1, &c1);
        __sincosf(phi0 + x.z, &s2, &c2);
        __sincosf(phi0 + x.w, &s3, &c3);
        As4[r][2 * jq]     = make_float4(m2at * c0, m2at * c1, m2at * c2, m2at * c3);
        As4[r][2 * jq + 1] = make_float4(p2at * s0, p2at * s1, p2at * s2, p2at * s3);

        float4 pv = *(const float4*)(P + (size_t)(o0 + r) * IDIM + j0 + 4 * jq);
        __sincosf(pv.x, &s0, &c0);
        __sincosf(pv.y, &s1, &c1);
        __sincosf(pv.z, &s2, &c2);
        __sincosf(pv.w, &s3, &c3);
        const int pr  = r >> 5;          // 0/1
        const int hi  = (r >> 4) & 1;    // 0/1
        const int tx_ = r & 15;
        float cs[4] = {c0, c1, c2, c3};
        float ss[4] = {s0, s1, s2, s3};
        #pragma unroll
        for (int jj = 0; jj < 4; ++jj) {
            float* cell = (float*)&SP4[4 * jq + jj][pr][tx_];
            cell[hi]     = cs[jj];
            cell[2 + hi] = ss[jj];
        }
    }
    __syncthreads();

    v2f acc[4][2];
    #pragma unroll
    for (int k = 0; k < 4; ++k) { acc[k][0] = (v2f){0.f, 0.f}; acc[k][1] = (v2f){0.f, 0.f}; }

    const v2f D2 = {Dc, Dc};

    #pragma unroll 2
    for (int jq = 0; jq < NJQ; ++jq) {
        // P operands for this j-quad: 8 x b128, shared across all k
        float4 q0[4], q1[4];
        #pragma unroll
        for (int j = 0; j < 4; ++j) {
            q0[j] = SP4[4 * jq + j][0][tx];
            q1[j] = SP4[4 * jq + j][1][tx];
        }
        #pragma unroll
        for (int k = 0; k < 4; ++k) {
            float4 mc4 = As4[ty + 16 * k][2 * jq];
            float4 ms4 = As4[ty + 16 * k][2 * jq + 1];
            float mcf[4] = {mc4.x, mc4.y, mc4.z, mc4.w};
            float msf[4] = {ms4.x, ms4.y, ms4.z, ms4.w};
            #pragma unroll
            for (int p = 0; p < 2; ++p) {
                const float4* q = (p == 0) ? q0 : q1;
                v2f d[4];
                #pragma unroll
                for (int j = 0; j < 4; ++j) {
                    v2f pc = {q[j].x, q[j].y};
                    v2f ps = {q[j].z, q[j].w};
                    v2f t = __builtin_elementwise_fma((v2f){msf[j], msf[j]}, ps, D2);
                    d[j]  = __builtin_elementwise_fma((v2f){mcf[j], mcf[j]}, pc, t);
                }
                // quad-rcp over the 4 j's, vectorized over the o-pair
                v2f p01 = d[0] * d[1], p23 = d[2] * d[3];
                v2f s01 = d[0] + d[1], s23 = d[2] + d[3];
                v2f n = __builtin_elementwise_fma(s01, p23, s23 * p01);
                v2f qq = p01 * p23;
                v2f r = {__builtin_amdgcn_rcpf(qq.x), __builtin_amdgcn_rcpf(qq.y)};
                acc[k][p] = __builtin_elementwise_fma(n, r, acc[k][p]);
            }
        }
    }

    // ---- atomic epilogue: base folded in as +ZBASE per z-plane ----
    #pragma unroll
    for (int k = 0; k < 4; ++k)
        #pragma unroll
        for (int p = 0; p < 2; ++p) {
            int b = b0 + ty + 16 * k;
            int o = o0 + p * 32 + tx;
            unsafeAtomicAdd(&Out[(size_t)b * ODIM + o],      fmaf(Cnum, acc[k][p].x, ZBASE));
            unsafeAtomicAdd(&Out[(size_t)b * ODIM + o + 16], fmaf(Cnum, acc[k][p].y, ZBASE));
        }
}

extern "C" void kernel_launch(void* const* d_in, const int* in_sizes, int n_in,
                              void* d_out, int out_size, void* d_ws, size_t ws_size,
                              hipStream_t stream) {
    const float* X = (const float*)d_in[0];   // input_matrix [2048,256] f32
    const float* P = (const float*)d_in[1];   // phase_offset [256,256] f32
    float* Out = (float*)d_out;               // [2048,256] f32

    const double RADIUS = 5e-6, KAPPA = 0.1, N_EFF = 3.48, LAMBDA = 1.55e-6, LOSS_A = 0.99;
    const double TWO_PI = 6.283185307179586476925286766559;
    const double t  = sqrt(1.0 - KAPPA);
    const double a  = LOSS_A;
    const double at = a * t;
    const double phi0 = fmod(TWO_PI * N_EFF * (TWO_PI * RADIUS) / LAMBDA, TWO_PI);
    const double D    = 1.0 + at * at;
    const double Cnum = (t * t - 1.0) * (1.0 - a * a);   // num - den (constant)

    // 4 o-tiles x 32 b-tiles x 16 j-splits = 2048 blocks of 256 thr (6/CU, 24 waves/CU)
    dim3 grid(ODIM / 64, BDIM / 64, NZ);
    photonic_fused<<<grid, 256, 0, stream>>>(
        X, P, Out,
        (float)phi0, (float)(-2.0 * at), (float)(2.0 * at),
        (float)D, (float)Cnum);
}

// Round 6
// 73.676 us; speedup vs baseline: 1.1538x; 1.1538x over previous
//
#include <hip/hip_runtime.h>
#include <math.h>

// Problem dims (fixed by reference)
#define BDIM 2048
#define ODIM 256
#define IDIM 256
#define NZ   8                      // j-splits
#define JBLK (IDIM / NZ)            // 32 j per block
#define NJQ  (JBLK / 4)             // 8 j-quads
#define ZBASE ((float)(IDIM / NZ))  // 32.0f; per-z share of the +IDIM base

typedef float v2f __attribute__((ext_vector_type(2)));

// out[b,o] = IDIM + C * sum_j 1/(D - 2at*cos(phi0 + x[b,j] + p[o,j]))
//   C = (t^2-1)(1-a^2),  D = 1+(at)^2
// cos(x'+p) = cos x' cos p - sin x' sin p =>
//   den = D + mc*pc + ms*ps,  mc=-2at*cos(phi0+x), ms=2at*sin(phi0+x)
//
// R15: model fit from R9/R10/R13 (clean rows): t = 336/waves_per_CU +
// 11us*(LDS_insts/524k). NZ=16 adds ~+11us of atomic cost (R11/R14) and
// VGPR caps < ~90 spill (R11/R14), so: NZ=8, 256thr, 4b x 4o (524k LDS
// insts) and raise w via LDS size. R9's 33.8KB = 32KB payload + 1.4KB
// pad. Swap the As4 pad for an XOR column swizzle c' = c ^ ((r&3)<<1):
// hot-loop A-reads (rows ty+16k; ty&3 spans 0..3 per wave) hit bank-quads
// {c,c^2,c^4,c^6} mod 8 -> conflict-free with ZERO pad. LDS = exactly
// 32KB -> 5 blocks/CU (5*32768 = 160KiB exactly) = 20 waves/CU.
// launch_bounds(256,5): VGPR cap 102 >= ~90 working set (no spill).
// Pred: kernel = 336/20 + 11 = 27.8us -> dur ~68-69.

#define SWZ(r, c) ((c) ^ (((r) & 3) << 1))

__global__ __launch_bounds__(256, 5)
void photonic_fused(const float* __restrict__ X,   // [BDIM][IDIM]
                    const float* __restrict__ P,   // [ODIM][IDIM]
                    float* __restrict__ Out,       // [BDIM][ODIM] (+= semantics)
                    float phi0, float m2at, float p2at,
                    float Dc, float Cnum) {
    __shared__ float4 As4[64][16];       // 16384 B dense, XOR-swizzled columns
    __shared__ float4 SP4[JBLK][2][16];  // 16384 B

    const int tid = threadIdx.x;
    const int tx  = tid & 15;            // o sub-index
    const int ty  = tid >> 4;            // b sub-index 0..15
    const int o0  = blockIdx.x * 64;
    const int b0  = blockIdx.y * 64;
    const int j0  = blockIdx.z * JBLK;

    // ---- fused prologue: sincos margins straight into f32 LDS ----
    #pragma unroll
    for (int i = 0; i < 2; ++i) {
        const int r  = (tid >> 3) + 32 * i;   // 0..63
        const int jq = tid & 7;               // 0..7
        float s0, c0, s1, c1, s2, c2, s3, c3;

        float4 x = *(const float4*)(X + (size_t)(b0 + r) * IDIM + j0 + 4 * jq);
        __sincosf(phi0 + x.x, &s0, &c0);
        __sincosf(phi0 + x.y, &s1, &c1);
        __sincosf(phi0 + x.z, &s2, &c2);
        __sincosf(phi0 + x.w, &s3, &c3);
        As4[r][SWZ(r, 2 * jq)]     = make_float4(m2at * c0, m2at * c1, m2at * c2, m2at * c3);
        As4[r][SWZ(r, 2 * jq + 1)] = make_float4(p2at * s0, p2at * s1, p2at * s2, p2at * s3);

        float4 pv = *(const float4*)(P + (size_t)(o0 + r) * IDIM + j0 + 4 * jq);
        __sincosf(pv.x, &s0, &c0);
        __sincosf(pv.y, &s1, &c1);
        __sincosf(pv.z, &s2, &c2);
        __sincosf(pv.w, &s3, &c3);
        const int pr  = r >> 5;               // 0/1
        const int hi  = (r >> 4) & 1;         // 0/1
        const int tx_ = r & 15;
        float cs[4] = {c0, c1, c2, c3};
        float ss[4] = {s0, s1, s2, s3};
        #pragma unroll
        for (int jj = 0; jj < 4; ++jj) {
            float* cell = (float*)&SP4[4 * jq + jj][pr][tx_];
            cell[hi]     = cs[jj];
            cell[2 + hi] = ss[jj];
        }
    }
    __syncthreads();

    v2f acc[4][2];
    #pragma unroll
    for (int k = 0; k < 4; ++k) { acc[k][0] = (v2f){0.f, 0.f}; acc[k][1] = (v2f){0.f, 0.f}; }

    const v2f D2 = {Dc, Dc};
    const int sw = (ty & 3) << 1;        // wave-constant per lane; (ty+16k)&3 == ty&3

    #pragma unroll 2
    for (int jq = 0; jq < NJQ; ++jq) {
        // P operands for this j-quad: 8 x b128, shared across all k
        float4 q0[4], q1[4];
        #pragma unroll
        for (int j = 0; j < 4; ++j) {
            q0[j] = SP4[4 * jq + j][0][tx];
            q1[j] = SP4[4 * jq + j][1][tx];
        }
        #pragma unroll
        for (int k = 0; k < 4; ++k) {
            float4 mc4 = As4[ty + 16 * k][(2 * jq) ^ sw];
            float4 ms4 = As4[ty + 16 * k][(2 * jq + 1) ^ sw];
            float mcf[4] = {mc4.x, mc4.y, mc4.z, mc4.w};
            float msf[4] = {ms4.x, ms4.y, ms4.z, ms4.w};
            #pragma unroll
            for (int p = 0; p < 2; ++p) {
                const float4* q = (p == 0) ? q0 : q1;
                v2f d[4];
                #pragma unroll
                for (int j = 0; j < 4; ++j) {
                    v2f pc = {q[j].x, q[j].y};
                    v2f ps = {q[j].z, q[j].w};
                    v2f t = __builtin_elementwise_fma((v2f){msf[j], msf[j]}, ps, D2);
                    d[j]  = __builtin_elementwise_fma((v2f){mcf[j], mcf[j]}, pc, t);
                }
                // quad-rcp over the 4 j's, vectorized over the o-pair
                v2f p01 = d[0] * d[1], p23 = d[2] * d[3];
                v2f s01 = d[0] + d[1], s23 = d[2] + d[3];
                v2f n = __builtin_elementwise_fma(s01, p23, s23 * p01);
                v2f qq = p01 * p23;
                v2f r = {__builtin_amdgcn_rcpf(qq.x), __builtin_amdgcn_rcpf(qq.y)};
                acc[k][p] = __builtin_elementwise_fma(n, r, acc[k][p]);
            }
        }
    }

    // ---- atomic epilogue: base folded in as +ZBASE per z-plane ----
    #pragma unroll
    for (int k = 0; k < 4; ++k)
        #pragma unroll
        for (int p = 0; p < 2; ++p) {
            int b = b0 + ty + 16 * k;
            int o = o0 + p * 32 + tx;
            unsafeAtomicAdd(&Out[(size_t)b * ODIM + o],      fmaf(Cnum, acc[k][p].x, ZBASE));
            unsafeAtomicAdd(&Out[(size_t)b * ODIM + o + 16], fmaf(Cnum, acc[k][p].y, ZBASE));
        }
}

extern "C" void kernel_launch(void* const* d_in, const int* in_sizes, int n_in,
                              void* d_out, int out_size, void* d_ws, size_t ws_size,
                              hipStream_t stream) {
    const float* X = (const float*)d_in[0];   // input_matrix [2048,256] f32
    const float* P = (const float*)d_in[1];   // phase_offset [256,256] f32
    float* Out = (float*)d_out;               // [2048,256] f32

    const double RADIUS = 5e-6, KAPPA = 0.1, N_EFF = 3.48, LAMBDA = 1.55e-6, LOSS_A = 0.99;
    const double TWO_PI = 6.283185307179586476925286766559;
    const double t  = sqrt(1.0 - KAPPA);
    const double a  = LOSS_A;
    const double at = a * t;
    const double phi0 = fmod(TWO_PI * N_EFF * (TWO_PI * RADIUS) / LAMBDA, TWO_PI);
    const double D    = 1.0 + at * at;
    const double Cnum = (t * t - 1.0) * (1.0 - a * a);   // num - den (constant)

    // 4 o-tiles x 32 b-tiles x 8 j-splits = 1024 blocks of 256 thr (5/CU, 20 waves/CU)
    dim3 grid(ODIM / 64, BDIM / 64, NZ);
    photonic_fused<<<grid, 256, 0, stream>>>(
        X, P, Out,
        (float)phi0, (float)(-2.0 * at), (float)(2.0 * at),
        (float)D, (float)Cnum);
}